// Round 15
// baseline (146.646 us; speedup 1.0000x reference)
//
#include <hip/hip_runtime.h>

#define F 64
#define BN_EPS 1e-5f
#define NBLK 1024          // edge chunks for counting sort
#define BSH 7              // bucket = row >> 7 (128 rows/bucket)

typedef __attribute__((ext_vector_type(8))) short bf16x8;
typedef __attribute__((ext_vector_type(4))) float f32x4;

// f32 -> bf16 round-to-nearest-even
static __device__ __forceinline__ unsigned short f2bf(float x) {
    union { float f; unsigned u; } v; v.f = x;
    return (unsigned short)((v.u + 0x7fffu + ((v.u >> 16) & 1u)) >> 16);
}

// accumulate 8 bf16 (as uint4) into 8 f32
static __device__ __forceinline__ void acc8(float* a, uint4 t) {
    union { unsigned u; float f; } lo, hi;
    lo.u = t.x << 16; hi.u = t.x & 0xffff0000u; a[0] += lo.f; a[1] += hi.f;
    lo.u = t.y << 16; hi.u = t.y & 0xffff0000u; a[2] += lo.f; a[3] += hi.f;
    lo.u = t.z << 16; hi.u = t.z & 0xffff0000u; a[4] += lo.f; a[5] += hi.f;
    lo.u = t.w << 16; hi.u = t.w & 0xffff0000u; a[6] += lo.f; a[7] += hi.f;
}

// ---------------- P0: convert x to bf16 (into d_out lower half) --------------
__global__ __launch_bounds__(256) void cvt_kernel(
    const float4* __restrict__ x4,
    ushort4* __restrict__ xb4,
    int total4)
{
    const int stride = gridDim.x * blockDim.x;
    for (int i = blockIdx.x * blockDim.x + threadIdx.x; i < total4; i += stride) {
        const float4 v = x4[i];
        ushort4 o;
        o.x = f2bf(v.x); o.y = f2bf(v.y); o.z = f2bf(v.z); o.w = f2bf(v.w);
        xb4[i] = o;
    }
}

// ---------------- P1: per-chunk bucket histogram (LDS only) ----------------
__global__ __launch_bounds__(256) void p1_count(
    const int* __restrict__ row,
    const int* __restrict__ col,
    int* __restrict__ cnt,          // [NBLK][NB]
    int nEdges, int NB, int C)
{
    __shared__ int hist[1024];      // NB <= 1024
    const int t = threadIdx.x;
    const int b = blockIdx.x;
    for (int u = t; u < NB; u += 256) hist[u] = 0;
    __syncthreads();
    const int e0 = b * C;
    const int e1 = min(e0 + C, nEdges);
    for (int e = e0 + t; e < e1; e += 256) {
        const int r = row[e];
        const int c = col[e];
        if (r != c) atomicAdd(&hist[r >> BSH], 1);
    }
    __syncthreads();
    for (int u = t; u < NB; u += 256) cnt[(size_t)b * NB + u] = hist[u];
}

// ---------------- P2a: column scan of cnt (one block per bucket) -------------
__global__ __launch_bounds__(256) void p2a_colscan(
    int* __restrict__ cnt,
    int* __restrict__ colsum,
    int NB)
{
    __shared__ int vals[NBLK];
    __shared__ int part[256];
    const int u = blockIdx.x;
    const int t = threadIdx.x;
    for (int i = t; i < NBLK; i += 256) vals[i] = cnt[(size_t)i * NB + u];
    __syncthreads();
    int tmp[NBLK / 256];
    int s = 0;
    #pragma unroll
    for (int j = 0; j < NBLK / 256; ++j) { tmp[j] = s; s += vals[t * (NBLK / 256) + j]; }
    part[t] = s;
    __syncthreads();
    for (int off = 1; off < 256; off <<= 1) {
        const int a = (t >= off) ? part[t - off] : 0;
        __syncthreads();
        part[t] += a;
        __syncthreads();
    }
    const int prefix = part[t] - s;
    #pragma unroll
    for (int j = 0; j < NBLK / 256; ++j) vals[t * (NBLK / 256) + j] = prefix + tmp[j];
    __syncthreads();
    for (int i = t; i < NBLK; i += 256) cnt[(size_t)i * NB + u] = vals[i];
    if (t == 255) colsum[u] = part[255];
}

// ---------------- P2b: scan bucket totals -> gstart (single block) -----------
__global__ __launch_bounds__(1024) void p2b_scan(
    const int* __restrict__ colsum,
    int* __restrict__ gstart,
    int* __restrict__ starts,
    int NB, int n)
{
    __shared__ int tmp[1024];
    const int t = threadIdx.x;
    const int v = (t < NB) ? colsum[t] : 0;
    tmp[t] = v;
    __syncthreads();
    for (int off = 1; off < 1024; off <<= 1) {
        const int a = (t >= off) ? tmp[t - off] : 0;
        __syncthreads();
        tmp[t] += a;
        __syncthreads();
    }
    if (t < NB) gstart[t] = tmp[t] - v;
    if (t == 1023) { gstart[NB] = tmp[1023]; starts[n] = tmp[1023]; }
}

// ---------------- P3: scatter edges into bucket-grouped packed array ---------
__global__ __launch_bounds__(256) void p3_scatter(
    const int* __restrict__ row,
    const int* __restrict__ col,
    const int* __restrict__ cnt,
    const int* __restrict__ gstart,
    unsigned* __restrict__ packed,  // (row&127)<<25 | col
    int nEdges, int NB, int C)
{
    __shared__ int cur[1024];
    const int t = threadIdx.x;
    const int b = blockIdx.x;
    for (int u = t; u < NB; u += 256) cur[u] = gstart[u] + cnt[(size_t)b * NB + u];
    __syncthreads();
    const int e0 = b * C;
    const int e1 = min(e0 + C, nEdges);
    for (int e = e0 + t; e < e1; e += 256) {
        const int r = row[e];
        const int c = col[e];
        if (r != c) {
            const int slot = atomicAdd(&cur[r >> BSH], 1);
            packed[slot] = ((unsigned)(r & 127) << 25) | (unsigned)c;
        }
    }
}

// ---------------- P4: per-bucket counting sort -> CSR (starts, col_sorted) ---
__global__ __launch_bounds__(256) void p4_sort(
    const unsigned* __restrict__ packed,
    const int* __restrict__ gstart,
    int* __restrict__ starts,
    int* __restrict__ col_sorted,
    int nNodes, int NB)
{
    __shared__ int hist[128];
    __shared__ int sc[128];
    const int t = threadIdx.x;
    const int u = blockIdx.x;
    const int e0 = gstart[u];
    const int e1 = gstart[u + 1];
    if (t < 128) hist[t] = 0;
    __syncthreads();
    for (int e = e0 + t; e < e1; e += 256) atomicAdd(&hist[packed[e] >> 25], 1);
    __syncthreads();
    if (t < 128) sc[t] = hist[t];
    __syncthreads();
    for (int off = 1; off < 128; off <<= 1) {
        int a = 0;
        if (t < 128 && t >= off) a = sc[t - off];
        __syncthreads();
        if (t < 128) sc[t] += a;
        __syncthreads();
    }
    if (t < 128) {
        const int st = e0 + sc[t] - hist[t];
        sc[t] = st;
        const int node = u * 128 + t;
        if (node < nNodes) starts[node] = st;
    }
    __syncthreads();
    for (int e = e0 + t; e < e1; e += 256) {
        const unsigned p = packed[e];
        const int slot = atomicAdd(&sc[p >> 25], 1);
        col_sorted[slot] = (int)(p & 0x1FFFFFFu);
    }
}

// ---------------- Kernel A: bf16 gather (8-lane groups, 16B loads) ------------
// One wave per node. group g = lane>>3 (8 groups), q = lane&7 (16B quad of row).
__global__ __launch_bounds__(256) void gather_kernel(
    const uint4* __restrict__ xb,        // bf16 x, [node][8 x 16B]
    const int* __restrict__ starts,
    const int* __restrict__ col_sorted,
    uint4* __restrict__ aggb,            // bf16 agg out (ws)
    int nNodes)
{
    const int lane = threadIdx.x & 63;
    const int w = threadIdx.x >> 6;
    const int r = blockIdx.x * 4 + w;
    if (r >= nNodes) return;

    const int g = lane >> 3;   // 0..7
    const int q = lane & 7;    // 0..7

    const int s  = starts[r];
    const int en = starts[r + 1];

    const uint4 uself = xb[(size_t)r * 8 + q];

    float a0[8] = {0,0,0,0,0,0,0,0};
    float a1[8] = {0,0,0,0,0,0,0,0};
    float a2[8] = {0,0,0,0,0,0,0,0};
    float a3[8] = {0,0,0,0,0,0,0,0};

    int e = s;
    for (; e + 32 <= en; e += 32) {
        const int c0 = col_sorted[e + g];
        const int c1 = col_sorted[e + 8 + g];
        const int c2 = col_sorted[e + 16 + g];
        const int c3 = col_sorted[e + 24 + g];
        const uint4 t0 = xb[(size_t)c0 * 8 + q];
        const uint4 t1 = xb[(size_t)c1 * 8 + q];
        const uint4 t2 = xb[(size_t)c2 * 8 + q];
        const uint4 t3 = xb[(size_t)c3 * 8 + q];
        acc8(a0, t0); acc8(a1, t1); acc8(a2, t2); acc8(a3, t3);
    }
    for (; e + 16 <= en; e += 16) {
        const int c0 = col_sorted[e + g];
        const int c1 = col_sorted[e + 8 + g];
        const uint4 t0 = xb[(size_t)c0 * 8 + q];
        const uint4 t1 = xb[(size_t)c1 * 8 + q];
        acc8(a0, t0); acc8(a1, t1);
    }
    for (; e + 8 <= en; e += 8) {
        const int c = col_sorted[e + g];
        acc8(a0, xb[(size_t)c * 8 + q]);
    }
    if (e + g < en) {
        const int c = col_sorted[e + g];
        acc8(a1, xb[(size_t)c * 8 + q]);
    }

    // combine depths, reduce across 8 groups, add self
    float v[8];
    #pragma unroll
    for (int j = 0; j < 8; ++j) {
        float vj = (a0[j] + a1[j]) + (a2[j] + a3[j]);
        vj += __shfl_xor(vj, 8, 64);
        vj += __shfl_xor(vj, 16, 64);
        vj += __shfl_xor(vj, 32, 64);
        v[j] = vj;
    }
    acc8(v, uself);   // v += self

    if (g == 0) {
        uint4 o;
        o.x = (unsigned)f2bf(v[0]) | ((unsigned)f2bf(v[1]) << 16);
        o.y = (unsigned)f2bf(v[2]) | ((unsigned)f2bf(v[3]) << 16);
        o.z = (unsigned)f2bf(v[4]) | ((unsigned)f2bf(v[5]) << 16);
        o.w = (unsigned)f2bf(v[6]) | ((unsigned)f2bf(v[7]) << 16);
        aggb[(size_t)r * 8 + q] = o;
    }
}

// ---------------- Kernel B: MFMA bf16 MLP + fused BN partial stats ------------
__global__ __launch_bounds__(256) void mlp_kernel(
    const unsigned short* __restrict__ aggbf,   // bf16 agg (ws)
    const float* __restrict__ W1,
    const float* __restrict__ b1,
    const float* __restrict__ W2,
    const float* __restrict__ b2,
    float* __restrict__ out_,                   // d_out (h2, f32)
    float* __restrict__ partial,                // [128][NP]
    int nNodes, int NP)
{
    __shared__ float sH[4][16][68];   // per-wave h1 [node][feat], padded
    __shared__ float sSum[4][64];
    __shared__ float sSq[4][64];

    const int tid  = threadIdx.x;
    const int lane = tid & 63;
    const int w    = tid >> 6;
    const int nb   = lane & 15;
    const int kg   = lane >> 4;
    const int kb   = kg * 8;

    bf16x8 w1f[2][4], w2f[2][4];
    #pragma unroll
    for (int s = 0; s < 2; ++s) {
        #pragma unroll
        for (int c = 0; c < 4; ++c) {
            #pragma unroll
            for (int e = 0; e < 8; ++e) {
                const int k = s * 32 + kb + e;
                w1f[s][c][e] = (short)f2bf(W1[k * 64 + c * 16 + nb]);
                w2f[s][c][e] = (short)f2bf(W2[k * 64 + c * 16 + nb]);
            }
        }
    }

    const int node0 = blockIdx.x * 64 + w * 16;

    int an = node0 + nb;
    if (an >= nNodes) an = nNodes - 1;
    const unsigned short* arow = aggbf + (size_t)an * 64;
    bf16x8 a[2];
    a[0] = *reinterpret_cast<const bf16x8*>(arow + kb);
    a[1] = *reinterpret_cast<const bf16x8*>(arow + 32 + kb);

    #pragma unroll
    for (int c = 0; c < 4; ++c) {
        const float bias = b1[c * 16 + nb];
        f32x4 acc = {bias, bias, bias, bias};
        acc = __builtin_amdgcn_mfma_f32_16x16x32_bf16(a[0], w1f[0][c], acc, 0, 0, 0);
        acc = __builtin_amdgcn_mfma_f32_16x16x32_bf16(a[1], w1f[1][c], acc, 0, 0, 0);
        #pragma unroll
        for (int r = 0; r < 4; ++r)
            sH[w][kg * 4 + r][c * 16 + nb] = fmaxf(acc[r], 0.0f);
    }
    __syncthreads();

    bf16x8 h[2];
    #pragma unroll
    for (int s = 0; s < 2; ++s)
        #pragma unroll
        for (int e = 0; e < 8; ++e)
            h[s][e] = (short)f2bf(sH[w][nb][s * 32 + kb + e]);

    #pragma unroll
    for (int c = 0; c < 4; ++c) {
        const float bias = b2[c * 16 + nb];
        f32x4 acc = {bias, bias, bias, bias};
        acc = __builtin_amdgcn_mfma_f32_16x16x32_bf16(h[0], w2f[0][c], acc, 0, 0, 0);
        acc = __builtin_amdgcn_mfma_f32_16x16x32_bf16(h[1], w2f[1][c], acc, 0, 0, 0);
        float sv = 0.0f, sq = 0.0f;
        #pragma unroll
        for (int r = 0; r < 4; ++r) {
            const int node = node0 + kg * 4 + r;
            const float vv = fmaxf(acc[r], 0.0f);
            if (node < nNodes) {
                out_[(size_t)node * 64 + c * 16 + nb] = vv;
                sv += vv;
                sq = fmaf(vv, vv, sq);
            }
        }
        sv += __shfl_xor(sv, 16, 64);
        sv += __shfl_xor(sv, 32, 64);
        sq += __shfl_xor(sq, 16, 64);
        sq += __shfl_xor(sq, 32, 64);
        if (kg == 0) {
            sSum[w][c * 16 + nb] = sv;
            sSq[w][c * 16 + nb] = sq;
        }
    }
    __syncthreads();

    if (tid < 128) {
        const int f = tid & 63;
        float t;
        if (tid < 64) t = sSum[0][f] + sSum[1][f] + sSum[2][f] + sSum[3][f];
        else          t = sSq[0][f] + sSq[1][f] + sSq[2][f] + sSq[3][f];
        partial[(size_t)tid * NP + blockIdx.x] = t;
    }
}

// ---------------- Kernel C1b: reduce partials -> stats (deterministic) --------
__global__ __launch_bounds__(256) void stats_reduce(
    const float* __restrict__ partial,   // [128][NP]
    float* __restrict__ stats,           // [128]
    int NP)
{
    __shared__ float red[256];
    const int f = blockIdx.x;            // 0..127
    const int t = threadIdx.x;
    float acc = 0.0f;
    for (int i = t; i < NP; i += 256) acc += partial[(size_t)f * NP + i];
    red[t] = acc;
    __syncthreads();
    for (int off = 128; off > 0; off >>= 1) {
        if (t < off) red[t] += red[t + off];
        __syncthreads();
    }
    if (t == 0) stats[f] = red[0];
}

// ---------------- Kernel C2: BN finalize + normalize in place (float4) --------
__global__ __launch_bounds__(256) void bn_normalize_kernel(
    float4* __restrict__ h,
    const float* __restrict__ stats,
    const float* __restrict__ gamma,
    const float* __restrict__ beta,
    int nNodes)
{
    __shared__ float sscale[F];
    __shared__ float sshift[F];
    if (threadIdx.x < F) {
        const int f = threadIdx.x;
        const float invN = 1.0f / (float)nNodes;
        const float mean = stats[f] * invN;
        const float var  = stats[F + f] * invN - mean * mean;
        const float inv  = rsqrtf(var + BN_EPS);
        const float g    = gamma[f];
        sscale[f] = inv * g;
        sshift[f] = beta[f] - mean * inv * g;
    }
    __syncthreads();

    const int total4 = nNodes * (F / 4);
    const int stride = gridDim.x * blockDim.x;
    for (int i = blockIdx.x * blockDim.x + threadIdx.x; i < total4; i += stride) {
        const int f0 = (i & 15) * 4;
        float4 v = h[i];
        v.x = fmaf(v.x, sscale[f0 + 0], sshift[f0 + 0]);
        v.y = fmaf(v.y, sscale[f0 + 1], sshift[f0 + 1]);
        v.z = fmaf(v.z, sscale[f0 + 2], sshift[f0 + 2]);
        v.w = fmaf(v.w, sscale[f0 + 3], sshift[f0 + 3]);
        h[i] = v;
    }
}

extern "C" void kernel_launch(void* const* d_in, const int* in_sizes, int n_in,
                              void* d_out, int out_size, void* d_ws, size_t ws_size,
                              hipStream_t stream)
{
    const float* x     = (const float*)d_in[0];
    const int*   eidx  = (const int*)d_in[1];   // [2, E]: row then col
    const float* W1    = (const float*)d_in[2];
    const float* b1    = (const float*)d_in[3];
    const float* W2    = (const float*)d_in[4];
    const float* b2    = (const float*)d_in[5];
    const float* gamma = (const float*)d_in[6];
    const float* beta  = (const float*)d_in[7];

    const int nNodes = in_sizes[0] / F;
    const int nEdges = in_sizes[1] / 2;
    const int* row = eidx;
    const int* col = eidx + nEdges;

    const int NB = (nNodes + 127) >> BSH;
    const int C  = (nEdges + NBLK - 1) / NBLK;
    const int NP = (nNodes + 63) / 64;         // mlp blocks

    // workspace layout; 256B-aligned. LIFETIME-SIZED UNIONS (round-14 crash fix):
    //   cntX   = cnt[NBLK*NB] (P1-P3)  UNION  col_sorted[nEdges] (P4-gather)
    //   packedX= packed[nEdges] (P3-P4) UNION  aggbf[nNodes*64 bf16] (gather-mlp)
    char* wsp = (char*)d_ws;
    auto alloc = [&](size_t bytes) -> char* {
        char* p = wsp;
        wsp += (bytes + 255) & ~(size_t)255;
        return p;
    };
    size_t cnt_bytes = (size_t)NBLK * NB * 4;
    size_t cs_bytes  = ((size_t)nEdges + 16) * 4;
    size_t pk_bytes  = (size_t)nEdges * 4;
    size_t ag_bytes  = (size_t)nNodes * F * 2;

    float*    stats      = (float*)alloc(128 * 4);
    float*    partial    = (float*)alloc((size_t)128 * NP * 4);
    int*      gstart     = (int*)alloc((size_t)(NB + 1) * 4);
    int*      colsum     = (int*)alloc((size_t)NB * 4);
    int*      starts     = (int*)alloc((size_t)(nNodes + 1) * 4);
    char*     cntX       = alloc(cnt_bytes > cs_bytes ? cnt_bytes : cs_bytes);
    int*      cnt        = (int*)cntX;
    int*      col_sorted = (int*)cntX;
    char*     packedX    = alloc(pk_bytes > ag_bytes ? pk_bytes : ag_bytes);
    unsigned* packed     = (unsigned*)packedX;
    unsigned short* aggbf = (unsigned short*)packedX;

    ushort4* xb4 = (ushort4*)d_out;    // bf16 x in d_out until gather completes
    float* hbuf = (float*)d_out;

    cvt_kernel<<<2048, 256, 0, stream>>>((const float4*)x, xb4, nNodes * 16);

    p1_count  <<<NBLK, 256, 0, stream>>>(row, col, cnt, nEdges, NB, C);
    p2a_colscan<<<NB, 256, 0, stream>>>(cnt, colsum, NB);
    p2b_scan  <<<1, 1024, 0, stream>>>(colsum, gstart, starts, NB, nNodes);
    p3_scatter<<<NBLK, 256, 0, stream>>>(row, col, cnt, gstart, packed, nEdges, NB, C);
    p4_sort   <<<NB, 256, 0, stream>>>(packed, gstart, starts, col_sorted, nNodes, NB);

    gather_kernel<<<(nNodes + 3) / 4, 256, 0, stream>>>(
        (const uint4*)xb4, starts, col_sorted, (uint4*)aggbf, nNodes);

    mlp_kernel<<<NP, 256, 0, stream>>>(
        aggbf, W1, b1, W2, b2, hbuf, partial, nNodes, NP);

    stats_reduce<<<128, 256, 0, stream>>>(partial, stats, NP);
    bn_normalize_kernel<<<2048, 256, 0, stream>>>((float4*)hbuf, stats, gamma, beta, nNodes);
}